// Round 9
// baseline (583.027 us; speedup 1.0000x reference)
//
#include <hip/hip_runtime.h>
#include <hip/hip_fp16.h>

#define NN 100000
#define NE 1600000
#define FD 128
#define OS 512   // output row stride: [feat | h1 | h2 | h3]
#define LDA 136  // LDS row stride in bf16 elems (128 + 8 pad -> bank-conflict-free)
#define NBKT 196 // buckets of 512 nodes: (99999>>9)=195 -> 196 buckets
#define PCH 4096 // edges per block in partition pass

typedef __attribute__((ext_vector_type(8))) short short8;
typedef __attribute__((ext_vector_type(4))) float f32x4;

__device__ __forceinline__ short f2bf(float x) {
    unsigned u = __float_as_uint(x);
    u = (u + 0x7fff + ((u >> 16) & 1)) >> 16;   // round-to-nearest-even
    return (short)u;
}

// ---------------- init: out cols 0:128 = feat (NT); hb = bf16(feat) ----------------
__global__ void k_init_out(const float* __restrict__ feat, float* __restrict__ out,
                           short* __restrict__ hb) {
    const size_t total = (size_t)NN * 32;  // float4s per feat row
    for (size_t i = (size_t)blockIdx.x * blockDim.x + threadIdx.x; i < total;
         i += (size_t)gridDim.x * blockDim.x) {
        size_t n = i >> 5;
        int c4 = (int)(i & 31);
        f32x4 v = ((const f32x4*)feat)[n * 32 + c4];
        __builtin_nontemporal_store(v, ((f32x4*)(out + n * OS)) + c4);
        short4 b;
        b.x = f2bf(v.x); b.y = f2bf(v.y); b.z = f2bf(v.z); b.w = f2bf(v.w);
        *(short4*)(hb + n * FD + c4 * 4) = b;
    }
}

// ---------------- prep: Wt[l][n][k] = bf16(W_l[k][n]) ----------------
__global__ void k_prep_w(const float* __restrict__ W0, const float* __restrict__ W1,
                         const float* __restrict__ W2, short* __restrict__ Wt) {
    int i = blockIdx.x * blockDim.x + threadIdx.x;
    if (i >= 3 * FD * FD) return;
    int l = i >> 14, r = i & (FD * FD - 1);
    int n = r >> 7, k = r & 127;
    const float* W = (l == 0) ? W0 : ((l == 1) ? W1 : W2);
    Wt[i] = f2bf(W[k * FD + n]);   // i = l*16384 + n*128 + k
}

// ---------------- bucket histograms of src AND dst (no global random atomics) --
__global__ __launch_bounds__(256) void k_deg(const int* __restrict__ src,
                                             const int* __restrict__ dst,
                                             int* __restrict__ bktcnt_d,
                                             int* __restrict__ bktcnt_s) {
    __shared__ int hd[NBKT];
    __shared__ int hs[NBKT];
    for (int i = threadIdx.x; i < NBKT; i += 256) { hd[i] = 0; hs[i] = 0; }
    __syncthreads();
    const int total4 = NE / 4;
    for (int i = blockIdx.x * blockDim.x + threadIdx.x; i < total4;
         i += gridDim.x * blockDim.x) {
        int4 s = ((const int4*)src)[i];
        int4 d = ((const int4*)dst)[i];
        atomicAdd(&hs[s.x >> 9], 1); atomicAdd(&hs[s.y >> 9], 1);
        atomicAdd(&hs[s.z >> 9], 1); atomicAdd(&hs[s.w >> 9], 1);
        atomicAdd(&hd[d.x >> 9], 1); atomicAdd(&hd[d.y >> 9], 1);
        atomicAdd(&hd[d.z >> 9], 1); atomicAdd(&hd[d.w >> 9], 1);
    }
    __syncthreads();
    for (int i = threadIdx.x; i < NBKT; i += 256) {
        if (hd[i]) atomicAdd(&bktcnt_d[i], hd[i]);
        if (hs[i]) atomicAdd(&bktcnt_s[i], hs[i]);
    }
}

// ---------------- scans of both 196-bucket count arrays (1 block) ----------------
__global__ __launch_bounds__(256) void k_scan2(const int* __restrict__ bktcnt_d,
                                               const int* __restrict__ bktcnt_s,
                                               int* __restrict__ base_d,
                                               int* __restrict__ cur_d,
                                               int* __restrict__ base_s,
                                               int* __restrict__ cur_s) {
    __shared__ int sh[256];
    const int tid = threadIdx.x;
    int v = (tid < NBKT) ? bktcnt_d[tid] : 0;
    sh[tid] = v;
    __syncthreads();
    for (int off = 1; off < 256; off <<= 1) {
        int t = (tid >= off) ? sh[tid - off] : 0;
        __syncthreads();
        sh[tid] += t;
        __syncthreads();
    }
    int excl = sh[tid] - v;
    if (tid < NBKT) { base_d[tid] = excl; cur_d[tid] = excl; }
    if (tid == NBKT - 1) base_d[NBKT] = excl + v;   // == NE
    __syncthreads();
    v = (tid < NBKT) ? bktcnt_s[tid] : 0;
    sh[tid] = v;
    __syncthreads();
    for (int off = 1; off < 256; off <<= 1) {
        int t = (tid >= off) ? sh[tid - off] : 0;
        __syncthreads();
        sh[tid] += t;
        __syncthreads();
    }
    excl = sh[tid] - v;
    if (tid < NBKT) { base_s[tid] = excl; cur_s[tid] = excl; }
    if (tid == NBKT - 1) base_s[NBKT] = excl + v;   // == NE
}

// ---------------- P1: dual radix-partition (dst -> pairs, src -> local-id stream)
__global__ __launch_bounds__(256) void k_part(const int* __restrict__ src,
                                              const int* __restrict__ dst,
                                              int* __restrict__ cur_d,
                                              int* __restrict__ cur_s,
                                              int2* __restrict__ pairs,
                                              unsigned short* __restrict__ ssrc) {
    __shared__ int hd[NBKT], bd[NBKT], ld_[NBKT];
    __shared__ int hs_[NBKT], bs_[NBKT], ls_[NBKT];
    const int tid = threadIdx.x;
    const int e0 = blockIdx.x * PCH;
    for (int i = tid; i < NBKT; i += 256) { hd[i] = 0; ld_[i] = 0; hs_[i] = 0; ls_[i] = 0; }
    __syncthreads();
    int md[16], ms[16];
    #pragma unroll
    for (int k = 0; k < 16; ++k) {
        int e = e0 + k * 256 + tid;
        md[k] = (e < NE) ? dst[e] : -1;
        ms[k] = (e < NE) ? src[e] : -1;
    }
    #pragma unroll
    for (int k = 0; k < 16; ++k)
        if (md[k] >= 0) {
            atomicAdd(&hd[md[k] >> 9], 1);
            atomicAdd(&hs_[ms[k] >> 9], 1);
        }
    __syncthreads();
    for (int i = tid; i < NBKT; i += 256) {
        bd[i] = hd[i] ? atomicAdd(&cur_d[i], hd[i]) : 0;
        bs_[i] = hs_[i] ? atomicAdd(&cur_s[i], hs_[i]) : 0;
    }
    __syncthreads();
    #pragma unroll
    for (int k = 0; k < 16; ++k)
        if (md[k] >= 0) {
            int b = md[k] >> 9;
            int off = atomicAdd(&ld_[b], 1);
            pairs[bd[b] + off] = make_int2(ms[k], md[k]);
            int b2 = ms[k] >> 9;
            int off2 = atomicAdd(&ls_[b2], 1);
            ssrc[bs_[b2] + off2] = (unsigned short)(ms[k] & 511);
        }
}

// ---------------- P2 (merged): per-bucket CSR build + per-bucket out-degrees ---
// blocks [0,NBKT): dst-side build (row_ptr, col, inv_in); blocks [NBKT,2*NBKT):
// src-side out-degree histogram -> inv_out. All atomics are LDS.
__global__ __launch_bounds__(256) void k_build(const int2* __restrict__ pairs,
                                               const int* __restrict__ base_d,
                                               const unsigned short* __restrict__ ssrc,
                                               const int* __restrict__ base_s,
                                               int* __restrict__ row_ptr,
                                               int* __restrict__ col,
                                               float* __restrict__ inv_in,
                                               float* __restrict__ inv_out) {
    __shared__ int cnt_s[512];
    __shared__ int wsum[4];
    const int tid = threadIdx.x;
    if (blockIdx.x >= NBKT) {   // ---- src side: out-degrees ----
        const int b = blockIdx.x - NBKT;
        const int ebeg = base_s[b], eend = base_s[b + 1];
        cnt_s[tid] = 0; cnt_s[tid + 256] = 0;
        __syncthreads();
        for (int e = ebeg + tid; e < eend; e += 256)
            atomicAdd(&cnt_s[ssrc[e]], 1);
        __syncthreads();
        const int n0 = b << 9;
        const int g0 = n0 + tid, g1 = g0 + 256;
        if (g0 < NN) inv_out[g0] = rsqrtf((float)max(cnt_s[tid], 1));
        if (g1 < NN) inv_out[g1] = rsqrtf((float)max(cnt_s[tid + 256], 1));
        return;
    }
    // ---- dst side: CSR build ----
    const int b = blockIdx.x;
    const int lane = tid & 63, wid = tid >> 6;
    const int ebeg = base_d[b], eend = base_d[b + 1];
    const int n0 = b << 9;
    cnt_s[tid] = 0; cnt_s[tid + 256] = 0;
    __syncthreads();
    for (int e = ebeg + tid; e < eend; e += 256)
        atomicAdd(&cnt_s[pairs[e].y - n0], 1);
    __syncthreads();
    const int v0 = cnt_s[2 * tid], v1 = cnt_s[2 * tid + 1];
    const int sum2 = v0 + v1;
    int incl = sum2;
    #pragma unroll
    for (int off = 1; off < 64; off <<= 1) {
        int t = __shfl_up(incl, off, 64);
        if (lane >= off) incl += t;
    }
    if (lane == 63) wsum[wid] = incl;
    __syncthreads();
    if (tid == 0) {
        int c = 0;
        #pragma unroll
        for (int i = 0; i < 4; ++i) { int t = wsum[i]; wsum[i] = c; c += t; }
    }
    __syncthreads();
    const int e0 = wsum[wid] + incl - sum2;
    cnt_s[2 * tid] = e0;
    cnt_s[2 * tid + 1] = e0 + v0;
    const int g0 = n0 + 2 * tid, g1 = g0 + 1;
    if (g0 < NN) { row_ptr[g0] = ebeg + e0; inv_in[g0] = rsqrtf((float)max(v0, 1)); }
    if (g1 < NN) { row_ptr[g1] = ebeg + e0 + v0; inv_in[g1] = rsqrtf((float)max(v1, 1)); }
    if (b == NBKT - 1 && tid == 0) row_ptr[NN] = eend;
    __syncthreads();
    for (int e = ebeg + tid; e < eend; e += 256) {
        int2 p = pairs[e];
        int pos = atomicAdd(&cnt_s[p.y - n0], 1);
        col[ebeg + pos] = p.x;
    }
}

// ---------------- MFMA GEMM -> int8 row-scaled tmp ----------------
// A-input: hb (bf16, sequential 12.8 MB — replaces 51.2 MB strided fp32 read;
// staging is now a straight copy, no f2bf). tmp8[r][col_p] int8, per-row scale;
// col_p = m*8 + ct (orig col c = ct*16 + m) -> one 8 B store per row per lane.
__global__ __launch_bounds__(256) void k_gemm(const short* __restrict__ hb,
                                              const short* __restrict__ Wt,
                                              const float* __restrict__ inv_out,
                                              unsigned char* __restrict__ tmp8,
                                              float* __restrict__ scales) {
    __shared__ short Ws[FD * LDA];   // Wt[n][k], padded rows: 34 KB
    __shared__ short hA[64 * LDA];   // h tile bf16, padded rows: 17 KB
    const int tid = threadIdx.x;
    for (int i = tid; i < FD * 16; i += 256) {   // 2048 chunks of 8 bf16
        int n = i >> 4, c = i & 15;
        short8 v = *(const short8*)(Wt + n * FD + c * 8);
        *(short8*)(&Ws[n * LDA + c * 8]) = v;
    }
    const int row0 = blockIdx.x * 128;
    const int wid = tid >> 6, lane = tid & 63;
    const int m = lane & 15, quad = lane >> 4;

    for (int sub = 0; sub < 2; ++sub) {
        const int rbase = row0 + sub * 64;
        __syncthreads();   // sub0: Ws staged; sub>0: prev compute done before hA overwrite
        for (int i = tid; i < 64 * 16; i += 256) {   // short8 chunks (16 B)
            int r = i >> 4, c = i & 15;
            int gr = rbase + r;
            short8 v = {0, 0, 0, 0, 0, 0, 0, 0};
            if (gr < NN) v = *(const short8*)(hb + (size_t)gr * FD + c * 8);
            *(short8*)(&hA[r * LDA + c * 8]) = v;
        }
        __syncthreads();
        const int rtile = rbase + wid * 16;          // this wave's 16 rows
        short8 a0 = *(const short8*)(&hA[(wid * 16 + m) * LDA + 0 * 32 + quad * 8]);
        short8 a1 = *(const short8*)(&hA[(wid * 16 + m) * LDA + 1 * 32 + quad * 8]);
        short8 a2 = *(const short8*)(&hA[(wid * 16 + m) * LDA + 2 * 32 + quad * 8]);
        short8 a3 = *(const short8*)(&hA[(wid * 16 + m) * LDA + 3 * 32 + quad * 8]);
        float s0, s1, s2, s3;
        {
            int r = rtile + quad * 4;
            s0 = (r + 0 < NN) ? inv_out[r + 0] : 0.f;
            s1 = (r + 1 < NN) ? inv_out[r + 1] : 0.f;
            s2 = (r + 2 < NN) ? inv_out[r + 2] : 0.f;
            s3 = (r + 3 < NN) ? inv_out[r + 3] : 0.f;
        }
        f32x4 accs[8];
        #pragma unroll
        for (int ct = 0; ct < 8; ++ct) {
            f32x4 acc = {0.f, 0.f, 0.f, 0.f};
            short8 b0 = *(const short8*)(&Ws[(ct * 16 + m) * LDA + 0 * 32 + quad * 8]);
            short8 b1 = *(const short8*)(&Ws[(ct * 16 + m) * LDA + 1 * 32 + quad * 8]);
            short8 b2 = *(const short8*)(&Ws[(ct * 16 + m) * LDA + 2 * 32 + quad * 8]);
            short8 b3 = *(const short8*)(&Ws[(ct * 16 + m) * LDA + 3 * 32 + quad * 8]);
            acc = __builtin_amdgcn_mfma_f32_16x16x32_bf16(a0, b0, acc, 0, 0, 0);
            acc = __builtin_amdgcn_mfma_f32_16x16x32_bf16(a1, b1, acc, 0, 0, 0);
            acc = __builtin_amdgcn_mfma_f32_16x16x32_bf16(a2, b2, acc, 0, 0, 0);
            acc = __builtin_amdgcn_mfma_f32_16x16x32_bf16(a3, b3, acc, 0, 0, 0);
            acc[0] *= s0; acc[1] *= s1; acc[2] *= s2; acc[3] *= s3;
            accs[ct] = acc;
        }
        float pm0 = 0.f, pm1 = 0.f, pm2 = 0.f, pm3 = 0.f;
        #pragma unroll
        for (int ct = 0; ct < 8; ++ct) {
            pm0 = fmaxf(pm0, fabsf(accs[ct][0]));
            pm1 = fmaxf(pm1, fabsf(accs[ct][1]));
            pm2 = fmaxf(pm2, fabsf(accs[ct][2]));
            pm3 = fmaxf(pm3, fabsf(accs[ct][3]));
        }
        #pragma unroll
        for (int off = 1; off < 16; off <<= 1) {
            pm0 = fmaxf(pm0, __shfl_xor(pm0, off));
            pm1 = fmaxf(pm1, __shfl_xor(pm1, off));
            pm2 = fmaxf(pm2, __shfl_xor(pm2, off));
            pm3 = fmaxf(pm3, __shfl_xor(pm3, off));
        }
        const float is0 = pm0 > 0.f ? 127.f / pm0 : 0.f;
        const float is1 = pm1 > 0.f ? 127.f / pm1 : 0.f;
        const float is2 = pm2 > 0.f ? 127.f / pm2 : 0.f;
        const float is3 = pm3 > 0.f ? 127.f / pm3 : 0.f;
        const int r = rtile + quad * 4;
        if (m == 0) {
            const float inv127 = 1.f / 127.f;
            if (r + 3 < NN) {
                f32x4 sv = {pm0 * inv127, pm1 * inv127, pm2 * inv127, pm3 * inv127};
                *((f32x4*)(scales + r)) = sv;
            } else {
                if (r + 0 < NN) scales[r + 0] = pm0 * inv127;
                if (r + 1 < NN) scales[r + 1] = pm1 * inv127;
                if (r + 2 < NN) scales[r + 2] = pm2 * inv127;
                if (r + 3 < NN) scales[r + 3] = pm3 * inv127;
            }
        }
        unsigned long long w0 = 0ull, w1 = 0ull, w2 = 0ull, w3 = 0ull;
        #pragma unroll
        for (int ct = 0; ct < 8; ++ct) {
            unsigned char q0 = (unsigned char)(char)(int)rintf(accs[ct][0] * is0);
            unsigned char q1 = (unsigned char)(char)(int)rintf(accs[ct][1] * is1);
            unsigned char q2 = (unsigned char)(char)(int)rintf(accs[ct][2] * is2);
            unsigned char q3 = (unsigned char)(char)(int)rintf(accs[ct][3] * is3);
            w0 |= (unsigned long long)q0 << (8 * ct);
            w1 |= (unsigned long long)q1 << (8 * ct);
            w2 |= (unsigned long long)q2 << (8 * ct);
            w3 |= (unsigned long long)q3 << (8 * ct);
        }
        unsigned char* base = tmp8 + (size_t)r * FD + m * 8;
        if (r + 3 < NN) {
            *(unsigned long long*)(base + 0 * FD) = w0;
            *(unsigned long long*)(base + 1 * FD) = w1;
            *(unsigned long long*)(base + 2 * FD) = w2;
            *(unsigned long long*)(base + 3 * FD) = w3;
        } else {
            if (r + 0 < NN) *(unsigned long long*)(base + 0 * FD) = w0;
            if (r + 1 < NN) *(unsigned long long*)(base + 1 * FD) = w1;
            if (r + 2 < NN) *(unsigned long long*)(base + 2 * FD) = w2;
            if (r + 3 < NN) *(unsigned long long*)(base + 3 * FD) = w3;
        }
    }
}

// ---------------- gather: out[d] (NT) + bf16 h sidecar for next GEMM ----------
// 128 B int8 rows; col loads nontemporal (stream-once); out stores nontemporal
// (never re-read); hb written for layers 0,1 only.
__global__ __launch_bounds__(256) void k_gather(const unsigned char* __restrict__ tmp8,
                                                const float* __restrict__ scales,
                                                const int* __restrict__ row_ptr,
                                                const int* __restrict__ col,
                                                const float* __restrict__ inv_in,
                                                const float* __restrict__ bias,
                                                float* __restrict__ out, int off,
                                                short* __restrict__ hb) {
    __shared__ float ob_s[4][128];
    const int wid = threadIdx.x >> 6;
    const int lane = threadIdx.x & 63;
    const int half = lane >> 5;   // 0: even edges, 1: odd edges
    const int sl = lane & 31;     // 4 B (4 permuted cols) of the 128 B row per lane
    const int node = blockIdx.x * 4 + wid;
    if (node >= NN) return;
    const int beg = row_ptr[node], end = row_ptr[node + 1];
    float a0 = 0.f, a1 = 0.f, a2 = 0.f, a3 = 0.f;
    int j = beg + half;
    for (; j + 6 < end; j += 8) {   // 4 edges per half per iter -> 8/wave in flight
        int s0 = __builtin_nontemporal_load(col + j);
        int s1 = __builtin_nontemporal_load(col + j + 2);
        int s2 = __builtin_nontemporal_load(col + j + 4);
        int s3 = __builtin_nontemporal_load(col + j + 6);
        char4 c0 = *(const char4*)(tmp8 + (size_t)s0 * FD + sl * 4);
        char4 c1 = *(const char4*)(tmp8 + (size_t)s1 * FD + sl * 4);
        char4 c2 = *(const char4*)(tmp8 + (size_t)s2 * FD + sl * 4);
        char4 c3 = *(const char4*)(tmp8 + (size_t)s3 * FD + sl * 4);
        float f0 = scales[s0], f1 = scales[s1], f2 = scales[s2], f3 = scales[s3];
        a0 += f0 * (float)c0.x + f1 * (float)c1.x + f2 * (float)c2.x + f3 * (float)c3.x;
        a1 += f0 * (float)c0.y + f1 * (float)c1.y + f2 * (float)c2.y + f3 * (float)c3.y;
        a2 += f0 * (float)c0.z + f1 * (float)c1.z + f2 * (float)c2.z + f3 * (float)c3.z;
        a3 += f0 * (float)c0.w + f1 * (float)c1.w + f2 * (float)c2.w + f3 * (float)c3.w;
    }
    for (; j < end; j += 2) {
        int s0 = __builtin_nontemporal_load(col + j);
        char4 c0 = *(const char4*)(tmp8 + (size_t)s0 * FD + sl * 4);
        float f0 = scales[s0];
        a0 += f0 * (float)c0.x;
        a1 += f0 * (float)c0.y;
        a2 += f0 * (float)c0.z;
        a3 += f0 * (float)c0.w;
    }
    // fold even/odd halves (identical column ranges) -> both halves hold totals
    a0 += __shfl_xor(a0, 32);
    a1 += __shfl_xor(a1, 32);
    a2 += __shfl_xor(a2, 32);
    a3 += __shfl_xor(a3, 32);
    if (half == 0) {
        // un-permute via LDS (wave-local; per-wave DS ops complete in order)
        float av[4] = {a0, a1, a2, a3};
        #pragma unroll
        for (int k = 0; k < 4; ++k) {
            int jj = 4 * sl + k;                 // permuted col index
            int c = ((jj & 7) << 4) + (jj >> 3); // original col
            ob_s[wid][c] = av[k];
        }
        const float s = inv_in[node];
        f32x4 f4 = ((const f32x4*)ob_s[wid])[sl];
        const f32x4 bb = ((const f32x4*)bias)[sl];
        f32x4 r;
        r.x = fmaxf(f4.x * s + bb.x, 0.f);
        r.y = fmaxf(f4.y * s + bb.y, 0.f);
        r.z = fmaxf(f4.z * s + bb.z, 0.f);
        r.w = fmaxf(f4.w * s + bb.w, 0.f);
        __builtin_nontemporal_store(r, ((f32x4*)(out + (size_t)node * OS + off)) + sl);
        if (hb) {   // bf16 sidecar for next layer's GEMM (bit-identical to old f2bf staging)
            short4 hq;
            hq.x = f2bf(r.x); hq.y = f2bf(r.y); hq.z = f2bf(r.z); hq.w = f2bf(r.w);
            *(short4*)(hb + (size_t)node * FD + sl * 4) = hq;
        }
    }
}

extern "C" void kernel_launch(void* const* d_in, const int* in_sizes, int n_in,
                              void* d_out, int out_size, void* d_ws, size_t ws_size,
                              hipStream_t stream) {
    const float* feat = (const float*)d_in[0];
    const float* W0 = (const float*)d_in[1];
    const float* b0 = (const float*)d_in[2];
    const float* W1 = (const float*)d_in[3];
    const float* b1 = (const float*)d_in[4];
    const float* W2 = (const float*)d_in[5];
    const float* b2 = (const float*)d_in[6];
    const int* src = (const int*)d_in[7];
    const int* dst = (const int*)d_in[8];
    float* out = (float*)d_out;
    float* ws = (float*)d_ws;

    unsigned char* tmp8 = (unsigned char*)ws;          // NN*128 int8 = 12.8 MB
    short* hb = (short*)(ws + (size_t)NN * 32);        // NN*128 bf16 = 25.6 MB
    int2* pairs = (int2*)(ws + (size_t)NN * 96);       // NE int2 = 12.8 MB
    unsigned short* ssrc = (unsigned short*)(ws + (size_t)NN * 128);  // NE u16 = 3.2 MB
    float* scales = ws + (size_t)NN * 136;             // NN floats
    int* base2 = (int*)(ws + (size_t)NN * 137);        // counter region
    int* bktcnt_d = base2;                             // NBKT
    int* bktcnt_s = bktcnt_d + NBKT;                   // NBKT (contiguous for memset)
    int* base_d = bktcnt_s + NBKT;                     // NBKT+1
    int* cur_d = base_d + NBKT + 1;                    // NBKT
    int* base_s = cur_d + NBKT;                        // NBKT+1
    int* cur_s = base_s + NBKT + 1;                    // NBKT
    float* inv = (float*)(cur_s + NBKT);               // 2N floats (inv_out | inv_in)
    int* row_ptr = (int*)(inv + 2 * NN);               // N+1
    int* col = row_ptr + NN + 1;                       // NE
    short* Wt = (short*)(col + NE);                    // 3*FD*FD bf16

    hipMemsetAsync(bktcnt_d, 0, 2 * NBKT * sizeof(int), stream);
    k_init_out<<<4096, 256, 0, stream>>>(feat, out, hb);
    k_prep_w<<<(3 * FD * FD + 255) / 256, 256, 0, stream>>>(W0, W1, W2, Wt);
    k_deg<<<512, 256, 0, stream>>>(src, dst, bktcnt_d, bktcnt_s);
    k_scan2<<<1, 256, 0, stream>>>(bktcnt_d, bktcnt_s, base_d, cur_d, base_s, cur_s);
    k_part<<<(NE + PCH - 1) / PCH, 256, 0, stream>>>(src, dst, cur_d, cur_s, pairs, ssrc);
    k_build<<<2 * NBKT, 256, 0, stream>>>(pairs, base_d, ssrc, base_s, row_ptr, col,
                                          inv + NN, inv);

    const float* bs[3] = {b0, b1, b2};
    for (int l = 0; l < 3; ++l) {
        k_gemm<<<(NN + 127) / 128, 256, 0, stream>>>(hb, Wt + l * FD * FD, inv,
                                                     tmp8, scales);
        k_gather<<<(NN + 3) / 4, 256, 0, stream>>>(tmp8, scales, row_ptr, col, inv + NN,
                                                   bs[l], out, FD * (l + 1),
                                                   (l < 2) ? hb : (short*)nullptr);
    }
}